// Round 8
// baseline (440.820 us; speedup 1.0000x reference)
//
#include <hip/hip_runtime.h>
#include <math.h>

#define N_ROWS  65536
#define DIM     256
#define K_CODES 1024
#define BM 128
#define BN 256
#define BK 16

// d_out regions (floats): [0, 16777216) quantization (final), [16777216, +65536) indices (final).
// Scratch inside quantization region, fully overwritten by vq_gather (last kernel):
//   [0, 512K)   per-row per-codeblock (best, idx) pairs: row*8 + by*2
//   [4M, +1K)   e_sq    [5M, +64K)  x_sq   (XLA/LLVM VF8-IC4 fma-contracted reduce)
#define IOFF    ((size_t)N_ROWS * DIM)
#define SCR_OFF ((size_t)0)
#define ESQ_OFF ((size_t)(4 * 1024 * 1024))
#define XSQ_OFF ((size_t)(5 * 1024 * 1024))

// Contraction/reassociation-proof single-rounded fp32 ops (hipcc -ffp-contract=fast
// would re-fuse plain +/*; inline asm cannot be fused or reassociated).
__device__ __forceinline__ float mulrn(float a, float b) {
    float d; asm("v_mul_f32 %0, %1, %2" : "=v"(d) : "v"(a), "v"(b)); return d;
}
__device__ __forceinline__ float addrn(float a, float b) {
    float d; asm("v_add_f32 %0, %1, %2" : "=v"(d) : "v"(a), "v"(b)); return d;
}
__device__ __forceinline__ float subrn(float a, float b) {
    float d; asm("v_sub_f32 %0, %1, %2" : "=v"(d) : "v"(a), "v"(b)); return d;
}

// ------- LLVM-loop-vectorized (VF=8, IC=4, fma-contract) sum of squares ----
// Model of XLA:CPU fused mul+reduce under fast-math on a prefer-256b x86 host:
//   4 vector accs <8 x float>, loop step 32, acc_i = fma(v, v, acc_i), m=0..7;
//   tail: ((P0+P1)+P2)+P3 per lane; then reduce.fadd halving tree 4,2,1.
// 64 rows/block; 256 threads stage, threads 0..63 each own one row.
// LDS row stride 257 -> thread t elem k hits bank (t+k)%32: 2-way = free.
__global__ __launch_bounds__(256)
void vq_sumsq_llvm(const float* __restrict__ src, float* __restrict__ out) {
    __shared__ float lx[64 * 257];
    const int t = threadIdx.x;
    const size_t base = (size_t)blockIdx.x * 64 * 256;
#pragma unroll
    for (int q = 0; q < 16; ++q) {
        int idx4 = q * 256 + t;              // float4 index within 64x256 tile
        int row = idx4 >> 6, col4 = idx4 & 63;
        *(float4*)(lx + row * 257 + col4 * 4) = *(const float4*)(src + base + (size_t)idx4 * 4);
    }
    __syncthreads();
    if (t < 64) {
        const float* xr = lx + t * 257;
        float a[4][8];
#pragma unroll
        for (int i = 0; i < 4; ++i)
#pragma unroll
            for (int l = 0; l < 8; ++l) a[i][l] = 0.f;
#pragma unroll
        for (int m = 0; m < 8; ++m)
#pragma unroll
            for (int i = 0; i < 4; ++i)
#pragma unroll
                for (int l = 0; l < 8; ++l) {
                    float v = xr[m * 32 + i * 8 + l];
                    a[i][l] = fmaf(v, v, a[i][l]);   // contracted square+acc, single rounding
                }
        float c[8];
#pragma unroll
        for (int l = 0; l < 8; ++l)
            c[l] = addrn(addrn(addrn(a[0][l], a[1][l]), a[2][l]), a[3][l]);
        float u0 = addrn(c[0], c[4]), u1 = addrn(c[1], c[5]);
        float u2 = addrn(c[2], c[6]), u3 = addrn(c[3], c[7]);
        float w0 = addrn(u0, u2), w1 = addrn(u1, u3);
        out[blockIdx.x * 64 + t] = addrn(w0, w1);
    }
}

// ------- kernel 1: dot (sequential-k FMA chain == Eigen gebp) + combine -----
__global__ __launch_bounds__(256, 2)
void vq_scores(const float* __restrict__ x, const float* __restrict__ emb,
               const float* __restrict__ esq, const float* __restrict__ xsq,
               float* __restrict__ scratch) {
    __shared__ __align__(16) float xs[BM * BK];
    __shared__ __align__(16) float es[BK][BN];
    const int t    = threadIdx.x;
    const int rowT = t >> 4;
    const int ct   = t & 15;
    const int bm0  = blockIdx.x * BM;
    const int bn0  = blockIdx.y * BN;

    float acc[8][16];
#pragma unroll
    for (int i = 0; i < 8; ++i)
#pragma unroll
        for (int j = 0; j < 16; ++j) acc[i][j] = 0.f;

    for (int kt = 0; kt < DIM / BK; ++kt) {
        const int k0 = kt * BK;
        __syncthreads();
#pragma unroll
        for (int q = 0; q < 2; ++q) {
            int idx = q * 256 + t;
            int row = idx >> 2, kq = idx & 3;
            float4 v = *(const float4*)(x + (size_t)(bm0 + row) * DIM + k0 + kq * 4);
            int g = kq ^ ((row >> 3) & 3);
            *(float4*)(xs + row * BK + g * 4) = v;
        }
#pragma unroll
        for (int q = 0; q < 4; ++q) {
            int idx = q * 256 + t;
            int cp = idx >> 2, kq = idx & 3;
            float4 v = *(const float4*)(emb + (size_t)(bn0 + cp) * DIM + k0 + kq * 4);
            int kb = kq * 4;
            es[kb + 0][(cp + 4 * (kb + 0)) & (BN - 1)] = v.x;
            es[kb + 1][(cp + 4 * (kb + 1)) & (BN - 1)] = v.y;
            es[kb + 2][(cp + 4 * (kb + 2)) & (BN - 1)] = v.z;
            es[kb + 3][(cp + 4 * (kb + 3)) & (BN - 1)] = v.w;
        }
        __syncthreads();
#pragma unroll
        for (int kq = 0; kq < 4; ++kq) {
            float4 xf[8];
#pragma unroll
            for (int i = 0; i < 8; ++i)
                xf[i] = *(const float4*)(xs + (rowT * 8 + i) * BK + ((kq ^ (rowT & 3)) * 4));
#pragma unroll
            for (int kk = 0; kk < 4; ++kk) {
                const int k = kq * 4 + kk;
#pragma unroll
                for (int g = 0; g < 4; ++g) {
                    float4 ef = *(const float4*)(&es[k][(ct * 4 + g * 64 + 4 * k) & (BN - 1)]);
#pragma unroll
                    for (int i = 0; i < 8; ++i) {
                        float xv = (kk == 0) ? xf[i].x : (kk == 1) ? xf[i].y
                                 : (kk == 2) ? xf[i].z : xf[i].w;
                        acc[i][g * 4 + 0] = fmaf(xv, ef.x, acc[i][g * 4 + 0]);
                        acc[i][g * 4 + 1] = fmaf(xv, ef.y, acc[i][g * 4 + 1]);
                        acc[i][g * 4 + 2] = fmaf(xv, ef.z, acc[i][g * 4 + 2]);
                        acc[i][g * 4 + 3] = fmaf(xv, ef.w, acc[i][g * 4 + 3]);
                    }
                }
            }
        }
    }

    // epilogue (XLA fast-math contraction): t1 = fma(-2, dot, x_sq)  [1 rounding]
    //           s = fl(t1 + e_sq); argmax(-s) == argmin(s), min-index ties.
    float4 eq[4];
#pragma unroll
    for (int g = 0; g < 4; ++g)
        eq[g] = *(const float4*)(esq + bn0 + ct * 4 + g * 64);

#pragma unroll
    for (int i = 0; i < 8; ++i) {
        const float xq = xsq[bm0 + rowT * 8 + i];
        float best = INFINITY;
        int bidx = 0x7fffffff;
#pragma unroll
        for (int g = 0; g < 4; ++g) {
#pragma unroll
            for (int q = 0; q < 4; ++q) {
                float e2 = (q == 0) ? eq[g].x : (q == 1) ? eq[g].y
                         : (q == 2) ? eq[g].z : eq[g].w;
                float t1 = fmaf(-2.f, acc[i][g * 4 + q], xq);
                float s  = addrn(t1, e2);
                int c = bn0 + ct * 4 + g * 64 + q;
                if (s < best) { best = s; bidx = c; }
                else if (s == best && c < bidx) bidx = c;
            }
        }
#pragma unroll
        for (int m = 1; m < 16; m <<= 1) {
            float ob = __shfl_xor(best, m, 64);
            int   oi = __shfl_xor(bidx, m, 64);
            if (ob < best || (ob == best && oi < bidx)) { best = ob; bidx = oi; }
        }
        if (ct == 0) {
            size_t row = (size_t)(bm0 + rowT * 8 + i);
            scratch[row * 8 + blockIdx.y * 2 + 0] = best;
            scratch[row * 8 + blockIdx.y * 2 + 1] = (float)bidx;
        }
    }
}

// ------- kernel 2: merge 4 codeblock partials (min s, min index) -----------
__global__ void vq_reduce(const float* __restrict__ scratch, float* __restrict__ idx_out) {
    int row = blockIdx.x * 256 + threadIdx.x;
    float best = INFINITY;
    int bidx = 0x7fffffff;
#pragma unroll
    for (int b = 0; b < 4; ++b) {
        float ob = scratch[(size_t)row * 8 + b * 2 + 0];
        int   oi = (int)scratch[(size_t)row * 8 + b * 2 + 1];
        if (ob < best || (ob == best && oi < bidx)) { best = ob; bidx = oi; }
    }
    idx_out[row] = (float)bidx;
}

// ------- kernel 3: gather embedding rows ------------------------------------
__global__ void vq_gather(const float* __restrict__ emb, const float* __restrict__ idx_f,
                          float* __restrict__ qout) {
    int row = blockIdx.x * 4 + (threadIdx.x >> 6);
    int l   = threadIdx.x & 63;
    int idx = (int)idx_f[row];
    float4 v = *(const float4*)(emb + (size_t)idx * DIM + l * 4);
    *(float4*)(qout + (size_t)row * DIM + l * 4) = v;
}

extern "C" void kernel_launch(void* const* d_in, const int* in_sizes, int n_in,
                              void* d_out, int out_size, void* d_ws, size_t ws_size,
                              hipStream_t stream) {
    const float* x   = (const float*)d_in[0];
    const float* emb = (const float*)d_in[1];
    float* out     = (float*)d_out;
    float* esq     = out + ESQ_OFF;
    float* xsq     = out + XSQ_OFF;
    float* scratch = out + SCR_OFF;
    float* idxf    = out + IOFF;

    vq_sumsq_llvm<<<dim3(K_CODES / 64), dim3(256), 0, stream>>>(emb, esq);
    vq_sumsq_llvm<<<dim3(N_ROWS / 64), dim3(256), 0, stream>>>(x, xsq);
    vq_scores<<<dim3(N_ROWS / BM, K_CODES / BN), dim3(256), 0, stream>>>(x, emb, esq, xsq, scratch);
    vq_reduce<<<dim3(N_ROWS / 256), dim3(256), 0, stream>>>(scratch, idxf);
    vq_gather<<<dim3(N_ROWS / 4), dim3(256), 0, stream>>>(emb, idxf, out);
}

// Round 9
// 299.891 us; speedup vs baseline: 1.4699x; 1.4699x over previous
//
#include <hip/hip_runtime.h>
#include <math.h>

#define MROWS   65536
#define NCODES  1024
#define KD      256
#define MARGIN  0.1f

typedef unsigned short u16;
typedef __attribute__((ext_vector_type(8))) short bfrag;   // 8 bf16 = 4 VGPR
typedef __attribute__((ext_vector_type(4))) float f32x4;

// d_out: [0, 16777216) quant (final; holds Ah/Al bf16 until gather), [16777216,+65536) idx.
// d_ws:  [0,512K) Eh | [512K,1M) El | [1M,+4K) esq | [1M+64K,+256K) xsq
//        [1.5M,+2M) tw (per-row per-wn top2) | [3.5M] cnt | [3.5M+256,+256K) list
#define IOFF ((size_t)MROWS * KD)

// ---- asm-rounded fp32 add (contraction/reassociation-proof) ---------------
__device__ __forceinline__ float addrn(float a, float b) {
    float d; asm("v_add_f32 %0, %1, %2" : "=v"(d) : "v"(a), "v"(b)); return d;
}

// ---- manual RNE bf16 split ------------------------------------------------
__device__ __forceinline__ u16 f2bf(float f) {
    unsigned u = __float_as_uint(f);
    return (u16)((u + 0x7fffu + ((u >> 16) & 1u)) >> 16);
}
__device__ __forceinline__ float bf2f(u16 h) { return __uint_as_float(((unsigned)h) << 16); }

// ------- pack: fp32 [R][256] -> fragment-blocked bf16 hi/lo ----------------
// slot((r,k)) = ((rb*8 + kb)*64 + (r&15) + 16*((k>>3)&3))*8 + (k&7)
__global__ __launch_bounds__(256)
void vq_pack(const float* __restrict__ src, u16* __restrict__ dh, u16* __restrict__ dl,
             unsigned int* __restrict__ cnt) {
    if (cnt && blockIdx.x == 0 && threadIdx.x == 0) *cnt = 0;
    __shared__ __align__(16) float lx[16 * 260];
    const int t = threadIdx.x;
    const size_t base = (size_t)blockIdx.x * 16 * 256;
#pragma unroll
    for (int qq = 0; qq < 4; ++qq) {
        int i4 = qq * 256 + t;
        int row = i4 >> 6, col = (i4 & 63) * 4;
        *(float4*)(lx + row * 260 + col) = *(const float4*)(src + base + (size_t)i4 * 4);
    }
    __syncthreads();
#pragma unroll
    for (int i = 0; i < 2; ++i) {
        int s = t + 256 * i;
        int kb = s >> 6, lane = s & 63;
        int r = lane & 15, kg = lane >> 4;
        int k0 = kb * 32 + kg * 8;
        bfrag vh, vl;
#pragma unroll
        for (int j = 0; j < 8; ++j) {
            float v = lx[r * 260 + k0 + j];
            u16 h = f2bf(v);
            u16 l = f2bf(v - bf2f(h));
            vh[j] = (short)h; vl[j] = (short)l;
        }
        size_t off = (((size_t)blockIdx.x * 8 + kb) * 64 + lane) * 8;
        *(bfrag*)(dh + off) = vh;
        *(bfrag*)(dl + off) = vl;
    }
}

// ------- np/XLA-exact sum of squares (R8-verified bits) --------------------
__global__ __launch_bounds__(256)
void vq_sumsq_llvm(const float* __restrict__ src, float* __restrict__ out) {
    __shared__ float lx[64 * 257];
    const int t = threadIdx.x;
    const size_t base = (size_t)blockIdx.x * 64 * 256;
#pragma unroll
    for (int qq = 0; qq < 16; ++qq) {
        int idx4 = qq * 256 + t;
        int row = idx4 >> 6, col4 = idx4 & 63;
        *(float4*)(lx + row * 257 + col4 * 4) = *(const float4*)(src + base + (size_t)idx4 * 4);
    }
    __syncthreads();
    if (t < 64) {
        const float* xr = lx + t * 257;
        float a[4][8];
#pragma unroll
        for (int i = 0; i < 4; ++i)
#pragma unroll
            for (int l = 0; l < 8; ++l) a[i][l] = 0.f;
#pragma unroll
        for (int m = 0; m < 8; ++m)
#pragma unroll
            for (int i = 0; i < 4; ++i)
#pragma unroll
                for (int l = 0; l < 8; ++l) {
                    float v = xr[m * 32 + i * 8 + l];
                    a[i][l] = fmaf(v, v, a[i][l]);
                }
        float cc[8];
#pragma unroll
        for (int l = 0; l < 8; ++l)
            cc[l] = addrn(addrn(addrn(a[0][l], a[1][l]), a[2][l]), a[3][l]);
        float u0 = addrn(cc[0], cc[4]), u1 = addrn(cc[1], cc[5]);
        float u2 = addrn(cc[2], cc[6]), u3 = addrn(cc[3], cc[7]);
        out[blockIdx.x * 64 + t] = addrn(addrn(u0, u2), addrn(u1, u3));
    }
}

// ------- MFMA bf16-split GEMM + per-row top-2 ------------------------------
__global__ __launch_bounds__(256, 2)
void vq_gemm(const u16* __restrict__ Ah, const u16* __restrict__ Al,
             const u16* __restrict__ Eh, const u16* __restrict__ El,
             const float* __restrict__ esq, const float* __restrict__ xsq,
             float* __restrict__ tw) {
    __shared__ u16 lds[2][32][512];    // 64KB: frag 0..15 = A(mf*2+mat), 16..31 = B(nf*2+mat)
    const int t = threadIdx.x;
    const int wave = t >> 6, lane = t & 63;
    const int wm = wave >> 1, wn = wave & 1;
    const int q = lane >> 4, c = lane & 15;
    const int m0 = blockIdx.x * 128;
    const int mrb = blockIdx.x * 8;

    float xq[16];
#pragma unroll
    for (int mi = 0; mi < 4; ++mi)
#pragma unroll
        for (int j = 0; j < 4; ++j)
            xq[mi * 4 + j] = xsq[m0 + wm * 64 + mi * 16 + q * 4 + j];

    float rb_[16], rs_[16], ri_[16];
#pragma unroll
    for (int r = 0; r < 16; ++r) { rb_[r] = INFINITY; rs_[r] = INFINITY; ri_[r] = 0.f; }

    for (int nqi = 0; nqi < 8; ++nqi) {
        f32x4 acc[4][4];
#pragma unroll
        for (int mi = 0; mi < 4; ++mi)
#pragma unroll
            for (int ni = 0; ni < 4; ++ni) acc[mi][ni] = 0.f;

        auto STAGE = [&](int ks, int b) {
#pragma unroll
            for (int u = 0; u < 8; ++u) {
                int f = wave * 8 + u;
                const u16* srcp;
                if (f < 16) {
                    int mf = f >> 1, mat = f & 1;
                    const u16* A = mat ? Al : Ah;
                    srcp = A + ((((size_t)(mrb + mf)) * 8 + ks) * 64 + lane) * 8;
                } else {
                    int nf = (f - 16) >> 1, mat = f & 1;
                    const u16* B = mat ? El : Eh;
                    srcp = B + ((((size_t)(nqi * 8 + nf)) * 8 + ks) * 64 + lane) * 8;
                }
                __builtin_amdgcn_global_load_lds((const unsigned int*)srcp,
                                                 (unsigned int*)&lds[b][f][0], 16, 0, 0);
            }
        };

        STAGE(0, 0);
        __syncthreads();
        for (int ks = 0; ks < 8; ++ks) {
            const int b = ks & 1;
            if (ks < 7) STAGE(ks + 1, b ^ 1);
            bfrag ah[4], alo[4], bh[4], blo[4];
#pragma unroll
            for (int mi = 0; mi < 4; ++mi) {
                ah[mi]  = *(const bfrag*)&lds[b][(wm * 4 + mi) * 2 + 0][lane * 8];
                alo[mi] = *(const bfrag*)&lds[b][(wm * 4 + mi) * 2 + 1][lane * 8];
            }
#pragma unroll
            for (int ni = 0; ni < 4; ++ni) {
                bh[ni]  = *(const bfrag*)&lds[b][16 + (wn * 4 + ni) * 2 + 0][lane * 8];
                blo[ni] = *(const bfrag*)&lds[b][16 + (wn * 4 + ni) * 2 + 1][lane * 8];
            }
#pragma unroll
            for (int mi = 0; mi < 4; ++mi)
#pragma unroll
                for (int ni = 0; ni < 4; ++ni) {
                    acc[mi][ni] = __builtin_amdgcn_mfma_f32_16x16x32_bf16(ah[mi],  bh[ni],  acc[mi][ni], 0, 0, 0);
                    acc[mi][ni] = __builtin_amdgcn_mfma_f32_16x16x32_bf16(alo[mi], bh[ni],  acc[mi][ni], 0, 0, 0);
                    acc[mi][ni] = __builtin_amdgcn_mfma_f32_16x16x32_bf16(ah[mi],  blo[ni], acc[mi][ni], 0, 0, 0);
                }
            __syncthreads();
        }
        // epilogue: s = -2*dot + xsq + esq (approx ok; margin covers), top-2 per row
        float e2[4];
#pragma unroll
        for (int ni = 0; ni < 4; ++ni)
            e2[ni] = esq[nqi * 128 + wn * 64 + ni * 16 + c];
#pragma unroll
        for (int mi = 0; mi < 4; ++mi)
#pragma unroll
            for (int j = 0; j < 4; ++j) {
                float b1 = INFINITY, s2 = INFINITY, bi = 0.f;
#pragma unroll
                for (int ni = 0; ni < 4; ++ni) {
                    float sc = fmaf(-2.f, acc[mi][ni][j], xq[mi * 4 + j]) + e2[ni];
                    float ci = (float)(nqi * 128 + wn * 64 + ni * 16 + c);
                    if (sc < b1) { s2 = b1; b1 = sc; bi = ci; }
                    else if (sc < s2) s2 = sc;
                }
#pragma unroll
                for (int mm = 1; mm < 16; mm <<= 1) {
                    float ob = __shfl_xor(b1, mm, 64);
                    float os = __shfl_xor(s2, mm, 64);
                    float oi = __shfl_xor(bi, mm, 64);
                    if (ob < b1) { s2 = fminf(b1, os); b1 = ob; bi = oi; }
                    else         { s2 = fminf(s2, fminf(ob, os)); }
                }
                int r = mi * 4 + j;
                if (b1 < rb_[r]) { rs_[r] = fminf(rb_[r], s2); rb_[r] = b1; ri_[r] = bi; }
                else             { rs_[r] = fminf(rs_[r], b1); }
            }
        __syncthreads();
    }
    if (c == 0) {
#pragma unroll
        for (int mi = 0; mi < 4; ++mi)
#pragma unroll
            for (int j = 0; j < 4; ++j) {
                int row = m0 + wm * 64 + mi * 16 + q * 4 + j;
                size_t o = (size_t)row * 8 + wn * 4;
                tw[o + 0] = rb_[mi * 4 + j];
                tw[o + 1] = rs_[mi * 4 + j];
                tw[o + 2] = ri_[mi * 4 + j];
            }
    }
}

// ------- merge wn partials; flag near-ties ---------------------------------
__global__ void vq_reduce2(const float* __restrict__ tw, float* __restrict__ idxf,
                           unsigned int* __restrict__ cnt, int* __restrict__ list) {
    int row = blockIdx.x * 256 + threadIdx.x;
    float b0 = tw[(size_t)row * 8 + 0], s0 = tw[(size_t)row * 8 + 1], i0 = tw[(size_t)row * 8 + 2];
    float b1 = tw[(size_t)row * 8 + 4], s1 = tw[(size_t)row * 8 + 5], i1 = tw[(size_t)row * 8 + 6];
    float b, s2, bi;
    if (b0 <= b1) { b = b0; bi = i0; s2 = fminf(s0, b1); }
    else          { b = b1; bi = i1; s2 = fminf(s1, b0); }
    idxf[row] = bi;
    if (s2 - b < MARGIN) {
        unsigned int pos = atomicAdd(cnt, 1u);
        list[pos] = row;
    }
}

// ------- bit-exact (R8-verified) refine for flagged rows -------------------
__global__ __launch_bounds__(256)
void vq_refine(const float* __restrict__ x, const float* __restrict__ emb,
               const float* __restrict__ esq, const float* __restrict__ xsq,
               const int* __restrict__ list, const unsigned int* __restrict__ cnt,
               float* __restrict__ idxf) {
    __shared__ __align__(16) float xs[256];
    __shared__ float sb[256];
    __shared__ int si[256];
    const int t = threadIdx.x;
    const unsigned int n = *cnt;
    for (unsigned int u = blockIdx.x; u < n; u += gridDim.x) {
        const int row = list[u];
        __syncthreads();
        if (t < 64)
            *(float4*)(xs + t * 4) = *(const float4*)(x + (size_t)row * 256 + t * 4);
        __syncthreads();
        const float xq = xsq[row];
        float best = INFINITY;
        int bi = 0x7fffffff;
#pragma unroll
        for (int qq = 0; qq < 4; ++qq) {
            const int cc = t + qq * 256;
            const float* er = emb + (size_t)cc * 256;
            float dot = 0.f;
#pragma unroll 8
            for (int k = 0; k < 256; ++k) dot = fmaf(xs[k], er[k], dot);
            float s = addrn(fmaf(-2.f, dot, xq), esq[cc]);
            if (s < best || (s == best && cc < bi)) { best = s; bi = cc; }
        }
        sb[t] = best; si[t] = bi;
        __syncthreads();
        for (int w = 128; w > 0; w >>= 1) {
            if (t < w) {
                float ob = sb[t + w]; int oi = si[t + w];
                if (ob < sb[t] || (ob == sb[t] && oi < si[t])) { sb[t] = ob; si[t] = oi; }
            }
            __syncthreads();
        }
        if (t == 0) idxf[row] = (float)si[0];
        __syncthreads();
    }
}

// ------- gather ------------------------------------------------------------
__global__ void vq_gather(const float* __restrict__ emb, const float* __restrict__ idx_f,
                          float* __restrict__ qout) {
    int row = blockIdx.x * 4 + (threadIdx.x >> 6);
    int l = threadIdx.x & 63;
    int idx = (int)idx_f[row];
    float4 v = *(const float4*)(emb + (size_t)idx * KD + l * 4);
    *(float4*)(qout + (size_t)row * KD + l * 4) = v;
}

extern "C" void kernel_launch(void* const* d_in, const int* in_sizes, int n_in,
                              void* d_out, int out_size, void* d_ws, size_t ws_size,
                              hipStream_t stream) {
    const float* x   = (const float*)d_in[0];
    const float* emb = (const float*)d_in[1];
    float* out  = (float*)d_out;
    float* idxf = out + IOFF;

    u16* Ah = (u16*)out;                         // 32MB
    u16* Al = (u16*)(out + 8 * 1024 * 1024);     // 32MB

    char* ws = (char*)d_ws;
    u16* Eh  = (u16*)(ws);
    u16* El  = (u16*)(ws + (512 << 10));
    float* esq = (float*)(ws + (1 << 20));
    float* xsq = (float*)(ws + (1 << 20) + (64 << 10));
    float* tw  = (float*)(ws + (1 << 20) + (512 << 10));
    unsigned int* cnt = (unsigned int*)(ws + (3 << 20) + (512 << 10));
    int* list = (int*)(ws + (3 << 20) + (512 << 10) + 256);

    vq_pack<<<dim3(MROWS / 16), dim3(256), 0, stream>>>(x, Ah, Al, cnt);
    vq_pack<<<dim3(NCODES / 16), dim3(256), 0, stream>>>(emb, Eh, El, nullptr);
    vq_sumsq_llvm<<<dim3(NCODES / 64), dim3(256), 0, stream>>>(emb, esq);
    vq_sumsq_llvm<<<dim3(MROWS / 64), dim3(256), 0, stream>>>(x, xsq);
    vq_gemm<<<dim3(MROWS / 128), dim3(256), 0, stream>>>(Ah, Al, Eh, El, esq, xsq, tw);
    vq_reduce2<<<dim3(MROWS / 256), dim3(256), 0, stream>>>(tw, idxf, cnt, list);
    vq_refine<<<dim3(512), dim3(256), 0, stream>>>(x, emb, esq, xsq, list, cnt, idxf);
    vq_gather<<<dim3(MROWS / 4), dim3(256), 0, stream>>>(emb, idxf, out);
}

// Round 10
// 258.408 us; speedup vs baseline: 1.7059x; 1.1605x over previous
//
#include <hip/hip_runtime.h>
#include <hip/hip_fp16.h>
#include <math.h>

#define MROWS   65536
#define NCODES  1024
#define KD      256
#define MARGIN  0.25f

typedef unsigned short u16;
typedef __attribute__((ext_vector_type(8))) _Float16 hfrag;  // 8 fp16 = 4 VGPR
typedef __attribute__((ext_vector_type(4))) float f32x4;

// d_out: [0, 32MB) Ah fp16 (scratch; overwritten by gather at end) | quant final [0,64MB) | idx at 64MB.
// d_ws:  [0,512K) Eh | [512K,+4K) esq | [1M,+2M) tw | [3.5M] cnt | [3.5M+256B,+256K) list
#define IOFF ((size_t)MROWS * KD)

// ---- asm-rounded fp32 add (contraction/reassociation-proof) ---------------
__device__ __forceinline__ float addrn(float a, float b) {
    float d; asm("v_add_f32 %0, %1, %2" : "=v"(d) : "v"(a), "v"(b)); return d;
}

// ------- pack: fp32 [R][256] -> fragment-blocked fp16 ----------------------
// frag layout: frag g = rb*8 + kb (rb = row-group-of-16, kb = k-block-of-32);
// within frag: lane l holds row (l&15), k = kb*32 + (l>>4)*8 + j  (j 0..7).
__global__ __launch_bounds__(256)
void vq_pack(const float* __restrict__ src, u16* __restrict__ dh,
             unsigned int* __restrict__ cnt) {
    if (cnt && blockIdx.x == 0 && threadIdx.x == 0) *cnt = 0;
    __shared__ __align__(16) float lx[16 * 260];
    const int t = threadIdx.x;
    const size_t base = (size_t)blockIdx.x * 16 * 256;
#pragma unroll
    for (int qq = 0; qq < 4; ++qq) {
        int i4 = qq * 256 + t;
        int row = i4 >> 6, col = (i4 & 63) * 4;
        *(float4*)(lx + row * 260 + col) = *(const float4*)(src + base + (size_t)i4 * 4);
    }
    __syncthreads();
#pragma unroll
    for (int i = 0; i < 2; ++i) {
        int s = t + 256 * i;
        int kb = s >> 6, lane = s & 63;
        int r = lane & 15, kg = lane >> 4;
        int k0 = kb * 32 + kg * 8;
        u16 vh[8];
#pragma unroll
        for (int j = 0; j < 8; ++j) {
            float v = lx[r * 260 + k0 + j];
            vh[j] = __half_as_ushort(__float2half(v));   // RNE
        }
        size_t off = (((size_t)blockIdx.x * 8 + kb) * 64 + lane) * 8;
        *(ulonglong2*)(dh + off) = *(ulonglong2*)vh;
    }
}

// ------- np/XLA-exact sum of squares (R8-verified bits), emb only ----------
__global__ __launch_bounds__(256)
void vq_sumsq_llvm(const float* __restrict__ src, float* __restrict__ out) {
    __shared__ float lx[64 * 257];
    const int t = threadIdx.x;
    const size_t base = (size_t)blockIdx.x * 64 * 256;
#pragma unroll
    for (int qq = 0; qq < 16; ++qq) {
        int idx4 = qq * 256 + t;
        int row = idx4 >> 6, col4 = idx4 & 63;
        *(float4*)(lx + row * 257 + col4 * 4) = *(const float4*)(src + base + (size_t)idx4 * 4);
    }
    __syncthreads();
    if (t < 64) {
        const float* xr = lx + t * 257;
        float a[4][8];
#pragma unroll
        for (int i = 0; i < 4; ++i)
#pragma unroll
            for (int l = 0; l < 8; ++l) a[i][l] = 0.f;
#pragma unroll
        for (int m = 0; m < 8; ++m)
#pragma unroll
            for (int i = 0; i < 4; ++i)
#pragma unroll
                for (int l = 0; l < 8; ++l) {
                    float v = xr[m * 32 + i * 8 + l];
                    a[i][l] = fmaf(v, v, a[i][l]);
                }
        float cc[8];
#pragma unroll
        for (int l = 0; l < 8; ++l)
            cc[l] = addrn(addrn(addrn(a[0][l], a[1][l]), a[2][l]), a[3][l]);
        float u0 = addrn(cc[0], cc[4]), u1 = addrn(cc[1], cc[5]);
        float u2 = addrn(cc[2], cc[6]), u3 = addrn(cc[3], cc[7]);
        out[blockIdx.x * 64 + t] = addrn(addrn(u0, u2), addrn(u1, u3));
    }
}

// ------- MFMA fp16 single-pass GEMM, A persistent in LDS -------------------
__global__ __launch_bounds__(256, 2)
void vq_gemm(const u16* __restrict__ Ah, const u16* __restrict__ Eh,
             const float* __restrict__ esq, float* __restrict__ tw) {
    extern __shared__ u16 lds[];          // 80 KB: A = 64 frags x 512 u16; B = 2x8 frags
    u16* ldsA = lds;
    u16* ldsB = lds + 64 * 512;
    const int t = threadIdx.x;
    const int wave = t >> 6, lane = t & 63;
    const int wm = wave >> 1, wn = wave & 1;
    const int q = lane >> 4, c = lane & 15;
    const int m0 = blockIdx.x * 128;
    const int mrb8 = blockIdx.x * 64;     // global A frag base = blockIdx*8 rowgroups * 8 kb

    // stage entire A tile (64 frags, 64 KB) — read from HBM exactly once
#pragma unroll
    for (int u = 0; u < 16; ++u) {
        int f = wave * 16 + u;
        const u16* srcp = Ah + ((size_t)(mrb8 + f) * 64 + lane) * 8;
        __builtin_amdgcn_global_load_lds((const unsigned int*)srcp,
                                         (unsigned int*)(ldsA + f * 512), 16, 0, 0);
    }
    // stage B for step 0 (nqi=0, ks=0) into buffer 0
#pragma unroll
    for (int u = 0; u < 2; ++u) {
        int nf = wave * 2 + u;
        const u16* srcp = Eh + (((size_t)nf * 8 + 0) * 64 + lane) * 8;
        __builtin_amdgcn_global_load_lds((const unsigned int*)srcp,
                                         (unsigned int*)(ldsB + nf * 512), 16, 0, 0);
    }
    __syncthreads();

    float b1[16], s2v[16], bi[16];
#pragma unroll
    for (int r = 0; r < 16; ++r) { b1[r] = INFINITY; s2v[r] = INFINITY; bi[r] = 0.f; }

    f32x4 acc[4][4];
#pragma unroll
    for (int mi = 0; mi < 4; ++mi)
#pragma unroll
        for (int ni = 0; ni < 4; ++ni) acc[mi][ni] = 0.f;

    for (int step = 0; step < 64; ++step) {
        const int nqi = step >> 3, ks = step & 7, p = step & 1;
        if (step < 63) {
            const int ns = step + 1, nq2 = ns >> 3, ks2 = ns & 7, p2 = ns & 1;
#pragma unroll
            for (int u = 0; u < 2; ++u) {
                int nf = wave * 2 + u;
                const u16* srcp = Eh + (((size_t)(nq2 * 8 + nf) * 8 + ks2) * 64 + lane) * 8;
                __builtin_amdgcn_global_load_lds((const unsigned int*)srcp,
                                                 (unsigned int*)(ldsB + (p2 * 8 + nf) * 512), 16, 0, 0);
            }
        }
        hfrag af[4], bfv[4];
#pragma unroll
        for (int mi = 0; mi < 4; ++mi)
            af[mi] = *(const hfrag*)(ldsA + ((wm * 4 + mi) * 8 + ks) * 512 + lane * 8);
#pragma unroll
        for (int ni = 0; ni < 4; ++ni)
            bfv[ni] = *(const hfrag*)(ldsB + (p * 8 + wn * 4 + ni) * 512 + lane * 8);
#pragma unroll
        for (int mi = 0; mi < 4; ++mi)
#pragma unroll
            for (int ni = 0; ni < 4; ++ni)
                acc[mi][ni] = __builtin_amdgcn_mfma_f32_16x16x32_f16(af[mi], bfv[ni], acc[mi][ni], 0, 0, 0);

        if (ks == 7) {
            // fold this nqi's 128 codes into lane-local top-2 (no shuffles here)
#pragma unroll
            for (int ni = 0; ni < 4; ++ni) {
                const int code = nqi * 128 + wn * 64 + ni * 16 + c;
                const float e2 = esq[code];
                const float ci = (float)code;
#pragma unroll
                for (int mi = 0; mi < 4; ++mi)
#pragma unroll
                    for (int j = 0; j < 4; ++j) {
                        const int r = mi * 4 + j;
                        float sc = fmaf(-2.f, acc[mi][ni][j], e2);
                        bool lt = sc < b1[r];
                        s2v[r] = fminf(s2v[r], lt ? b1[r] : sc);
                        if (lt) { b1[r] = sc; bi[r] = ci; }
                    }
            }
#pragma unroll
            for (int mi = 0; mi < 4; ++mi)
#pragma unroll
                for (int ni = 0; ni < 4; ++ni) acc[mi][ni] = 0.f;
        }
        __syncthreads();
    }

    // one cross-lane top-2 merge over the 16 c-lanes (within same q group)
#pragma unroll
    for (int r = 0; r < 16; ++r) {
#pragma unroll
        for (int mm = 1; mm < 16; mm <<= 1) {
            float ob = __shfl_xor(b1[r], mm, 64);
            float os = __shfl_xor(s2v[r], mm, 64);
            float oi = __shfl_xor(bi[r], mm, 64);
            if (ob < b1[r]) { s2v[r] = fminf(b1[r], os); b1[r] = ob; bi[r] = oi; }
            else            { s2v[r] = fminf(s2v[r], ob); }
        }
    }
    if (c == 0) {
#pragma unroll
        for (int mi = 0; mi < 4; ++mi)
#pragma unroll
            for (int j = 0; j < 4; ++j) {
                int row = m0 + wm * 64 + mi * 16 + q * 4 + j;
                size_t o = (size_t)row * 8 + wn * 4;
                int r = mi * 4 + j;
                tw[o + 0] = b1[r];
                tw[o + 1] = s2v[r];
                tw[o + 2] = bi[r];
            }
    }
}

// ------- merge wn partials; flag near-ties ---------------------------------
__global__ void vq_reduce2(const float* __restrict__ tw, float* __restrict__ idxf,
                           unsigned int* __restrict__ cnt, int* __restrict__ list) {
    int row = blockIdx.x * 256 + threadIdx.x;
    float b0 = tw[(size_t)row * 8 + 0], s0 = tw[(size_t)row * 8 + 1], i0 = tw[(size_t)row * 8 + 2];
    float b1 = tw[(size_t)row * 8 + 4], s1 = tw[(size_t)row * 8 + 5], i1 = tw[(size_t)row * 8 + 6];
    float b, s2, bidx;
    if (b0 <= b1) { b = b0; bidx = i0; s2 = fminf(s0, b1); }
    else          { b = b1; bidx = i1; s2 = fminf(s1, b0); }
    idxf[row] = bidx;
    if (s2 - b < MARGIN) {
        unsigned int pos = atomicAdd(cnt, 1u);
        list[pos] = row;
    }
}

// ------- bit-exact (R8-verified) refine; 16 rows/block, 4 rows/wave --------
__global__ __launch_bounds__(256)
void vq_refine(const float* __restrict__ x, const float* __restrict__ emb,
               const float* __restrict__ esq, const int* __restrict__ list,
               const unsigned int* __restrict__ cnt, float* __restrict__ idxf) {
    __shared__ __align__(16) float xs[16][260];
    __shared__ float xsq_s[16];
    const int t = threadIdx.x;
    const int wave = t >> 6, lane = t & 63;
    const unsigned int n = *cnt;
    for (unsigned int g = blockIdx.x; g * 16u < n; g += gridDim.x) {
        const unsigned int r0 = g * 16u;
        const int nr = (int)min(16u, n - r0);
        __syncthreads();
#pragma unroll
        for (int u = 0; u < 4; ++u) {
            int s = u * 256 + t;
            int rr = s >> 6, l4 = s & 63;
            if (rr < nr) {
                int row = list[r0 + rr];
                *(float4*)(&xs[rr][l4 * 4]) = *(const float4*)(x + (size_t)row * 256 + l4 * 4);
            }
        }
        __syncthreads();
        if (t < nr) {  // exact VF8-IC4 xsq for this row
            float a[4][8];
#pragma unroll
            for (int i = 0; i < 4; ++i)
#pragma unroll
                for (int l = 0; l < 8; ++l) a[i][l] = 0.f;
#pragma unroll
            for (int m = 0; m < 8; ++m)
#pragma unroll
                for (int i = 0; i < 4; ++i)
#pragma unroll
                    for (int l = 0; l < 8; ++l) {
                        float v = xs[t][m * 32 + i * 8 + l];
                        a[i][l] = fmaf(v, v, a[i][l]);
                    }
            float cc[8];
#pragma unroll
            for (int l = 0; l < 8; ++l)
                cc[l] = addrn(addrn(addrn(a[0][l], a[1][l]), a[2][l]), a[3][l]);
            float u0 = addrn(cc[0], cc[4]), u1 = addrn(cc[1], cc[5]);
            float u2 = addrn(cc[2], cc[6]), u3 = addrn(cc[3], cc[7]);
            xsq_s[t] = addrn(addrn(u0, u2), addrn(u1, u3));
        }
        __syncthreads();
        const int rbase = wave * 4;
        float best[4]; int bidx[4];
#pragma unroll
        for (int rr = 0; rr < 4; ++rr) { best[rr] = INFINITY; bidx[rr] = 0x7fffffff; }
        for (int qq = 0; qq < 16; ++qq) {
            const int code = lane * 16 + qq;
            const float* er = emb + (size_t)code * 256;
            float d0 = 0.f, d1 = 0.f, d2 = 0.f, d3 = 0.f;
#pragma unroll 4
            for (int k = 0; k < 256; ++k) {   // ascending-k single-chain fmaf per row
                float e = er[k];
                d0 = fmaf(xs[rbase + 0][k], e, d0);
                d1 = fmaf(xs[rbase + 1][k], e, d1);
                d2 = fmaf(xs[rbase + 2][k], e, d2);
                d3 = fmaf(xs[rbase + 3][k], e, d3);
            }
            const float e2 = esq[code];
            float sv[4] = { addrn(fmaf(-2.f, d0, xsq_s[rbase + 0]), e2),
                            addrn(fmaf(-2.f, d1, xsq_s[rbase + 1]), e2),
                            addrn(fmaf(-2.f, d2, xsq_s[rbase + 2]), e2),
                            addrn(fmaf(-2.f, d3, xsq_s[rbase + 3]), e2) };
#pragma unroll
            for (int rr = 0; rr < 4; ++rr)
                if (sv[rr] < best[rr] || (sv[rr] == best[rr] && code < bidx[rr])) {
                    best[rr] = sv[rr]; bidx[rr] = code;
                }
        }
#pragma unroll
        for (int rr = 0; rr < 4; ++rr) {
            float b = best[rr]; int bix = bidx[rr];
#pragma unroll
            for (int mm = 1; mm < 64; mm <<= 1) {
                float ob = __shfl_xor(b, mm, 64);
                int oi = __shfl_xor(bix, mm, 64);
                if (ob < b || (ob == b && oi < bix)) { b = ob; bix = oi; }
            }
            if (lane == 0 && rbase + rr < nr)
                idxf[list[r0 + rbase + rr]] = (float)bix;
        }
    }
}

// ------- gather ------------------------------------------------------------
__global__ void vq_gather(const float* __restrict__ emb, const float* __restrict__ idx_f,
                          float* __restrict__ qout) {
    int row = blockIdx.x * 4 + (threadIdx.x >> 6);
    int l = threadIdx.x & 63;
    int idx = (int)idx_f[row];
    float4 v = *(const float4*)(emb + (size_t)idx * KD + l * 4);
    *(float4*)(qout + (size_t)row * KD + l * 4) = v;
}

extern "C" void kernel_launch(void* const* d_in, const int* in_sizes, int n_in,
                              void* d_out, int out_size, void* d_ws, size_t ws_size,
                              hipStream_t stream) {
    const float* x   = (const float*)d_in[0];
    const float* emb = (const float*)d_in[1];
    float* out  = (float*)d_out;
    float* idxf = out + IOFF;

    u16* Ah = (u16*)out;                         // 32 MB scratch in quant region

    char* ws = (char*)d_ws;
    u16* Eh    = (u16*)(ws);
    float* esq = (float*)(ws + (512 << 10));
    float* tw  = (float*)(ws + (1 << 20));
    unsigned int* cnt = (unsigned int*)(ws + ((size_t)3 << 20) + (512 << 10));
    int* list = (int*)(ws + ((size_t)3 << 20) + (512 << 10) + 256);

    vq_pack<<<dim3(MROWS / 16), dim3(256), 0, stream>>>(x, Ah, cnt);
    vq_pack<<<dim3(NCODES / 16), dim3(256), 0, stream>>>(emb, Eh, nullptr);
    vq_sumsq_llvm<<<dim3(NCODES / 64), dim3(256), 0, stream>>>(emb, esq);
    vq_gemm<<<dim3(MROWS / 128), dim3(256), 81920, stream>>>(Ah, Eh, esq, tw);
    vq_reduce2<<<dim3(MROWS / 256), dim3(256), 0, stream>>>(tw, idxf, cnt, list);
    vq_refine<<<dim3(1024), dim3(256), 0, stream>>>(x, emb, esq, list, cnt, idxf);
    vq_gather<<<dim3(MROWS / 4), dim3(256), 0, stream>>>(emb, idxf, out);
}